// Round 2
// baseline (318.899 us; speedup 1.0000x reference)
//
#include <hip/hip_runtime.h>
#include <math.h>

#define MT 16        // batch rows per block
#define BSX 152      // row stride for sX/sB (152 % 32 == 24 -> rows land on distinct banks)
#define QS 65        // sQa row stride (65 % 32 == 1 -> action rows hit distinct banks)

// ---------------------------------------------------------------------------
// card encoding: ce = [val_emb[v], suit_emb[s]] + [type_emb[ct], 0...]
// ---------------------------------------------------------------------------
__device__ __forceinline__ void encode_card32(int c,
                                              const float* __restrict__ val_emb,
                                              const float* __restrict__ suit_emb,
                                              const float* __restrict__ type_emb,
                                              float* e) {
  bool inv = (c == 0) || (c == 53);
  int v = inv ? 0 : ((c - 1) % 13 + 1);
  int s = inv ? 0 : ((c - 1) / 13 + 1);
  int ct = (v == 11) ? 1 : (v == 12) ? 2 : (v == 13) ? 3 : 0;
#pragma unroll
  for (int i = 0; i < 16; ++i) e[i] = val_emb[v * 16 + i];
#pragma unroll
  for (int i = 0; i < 16; ++i) e[16 + i] = suit_emb[s * 16 + i];
#pragma unroll
  for (int i = 0; i < 8; ++i) e[i] += type_emb[ct * 8 + i];
}

// ---------------------------------------------------------------------------
// Single fused kernel. 16 batch rows / block, 256 threads, grid 1024.
// Shared buffers are ping-ponged (never updated in place):
//   sX[r][0:32) hand_ctx | [32:64) enemy | [64:96) strat_ctx | [96:150) discard
//     later: [0:64) t1, [64:128) P
//   sB[r][0:20) strat_in | [20:84) t64 | [100:132) V;  later: h1 / ctx
//   sW2: first used as action scratch (act_emb 30x32 @ [0:960),
//        combo 30x16 @ [960:1440)), then overwritten with as_w2 (64x32)
//   sQa[30][64] (stride 65), sMeta: strength/hasv/w3/b2
// ---------------------------------------------------------------------------
__global__ __launch_bounds__(256) void policy_fused(
    const int* __restrict__ hand_cards, const int* __restrict__ enemy_card,
    const int* __restrict__ hand_size, const float* __restrict__ game_state,
    const float* __restrict__ discard, const int* __restrict__ acards,
    const float* __restrict__ val_emb, const float* __restrict__ suit_emb,
    const float* __restrict__ type_emb,
    const float* __restrict__ ce_w1, const float* __restrict__ ce_b1,
    const float* __restrict__ ce_w2, const float* __restrict__ ce_b2,
    const float* __restrict__ he_wv, const float* __restrict__ he_bv,
    const float* __restrict__ he_wo, const float* __restrict__ he_bo,
    const float* __restrict__ se_w1, const float* __restrict__ se_b1,
    const float* __restrict__ se_w2, const float* __restrict__ se_b2,
    const float* __restrict__ atc_w1, const float* __restrict__ atc_b1,
    const float* __restrict__ atc_w2, const float* __restrict__ atc_b2,
    const float* __restrict__ as_w1, const float* __restrict__ as_b1,
    const float* __restrict__ as_w2, const float* __restrict__ as_b2,
    const float* __restrict__ as_w3, const float* __restrict__ as_b3,
    const float* __restrict__ cx_w1, const float* __restrict__ cx_b1,
    const float* __restrict__ cx_w2, const float* __restrict__ cx_b2,
    const float* __restrict__ cx_w3, const float* __restrict__ cx_b3,
    float* __restrict__ out) {
  __shared__ float sX[MT * BSX];     // 9.5 KB
  __shared__ float sB[MT * BSX];     // 9.5 KB
  __shared__ float sQa[30 * QS];     // 7.6 KB
  __shared__ float sW2[2048];        // 8 KB (action scratch, then as_w2)
  __shared__ float sMeta[128];       // strength[0:32) hasv[32:64) w3[64:96) b2[96:128)
  __shared__ float sTp[MT * 4];
  __shared__ float sLen[MT];

  const int tid = threadIdx.x;
  const int b0 = blockIdx.x * MT;

  // ---------------- P0: global loads + per-row features + action features ----
  for (int idx = tid; idx < MT * 54; idx += 256) {
    int r = idx / 54, k = idx - r * 54;
    sX[r * BSX + 96 + k] = discard[(size_t)b0 * 54 + idx];
  }
  for (int idx = tid; idx < MT * 10; idx += 256) {
    int r = idx / 10, k = idx - r * 10;
    sB[r * BSX + k] = game_state[(size_t)b0 * 10 + idx];
  }
  if (tid < MT) {
    const int b = b0 + tid;
    const float hsz = (float)hand_size[b];
    sLen[tid] = 8.0f / fmaxf(hsz, 1.0f);
    int aces = 0, faces = 0, low = 0, c1 = 0, c2 = 0, c3 = 0, c4 = 0;
#pragma unroll
    for (int i = 0; i < 8; ++i) {
      int c = hand_cards[b * 8 + i];
      int v = (c == 0) ? 0 : ((c - 1) % 13 + 1);
      int s = (c == 0) ? 0 : ((c - 1) / 13 + 1);
      aces += (v == 1);
      faces += (v >= 11 && v <= 13);
      low += (v >= 2 && v <= 6);
      c1 += (s == 1); c2 += (s == 2); c3 += (s == 3); c4 += (s == 4);
    }
    float sdiv = (float)((c1 > 0) + (c2 > 0) + (c3 > 0) + (c4 > 0)) * 0.25f;
    float hvr = (float)faces / (hsz + 1e-8f);
    float* si = &sB[tid * BSX];
    si[10] = hsz; si[11] = (float)aces; si[12] = (float)faces;
    si[13] = (float)low; si[14] = (float)c1; si[15] = (float)c2;
    si[16] = (float)c3; si[17] = (float)c4; si[18] = hvr; si[19] = sdiv;
    float e[32];
    encode_card32(enemy_card[b], val_emb, suit_emb, type_emb, e);
#pragma unroll
    for (int i = 0; i < 32; ++i) sX[tid * BSX + 32 + i] = e[i];
  }
  if (tid < 30) {  // action-side features -> scratch in sW2 + sMeta
    int c[4];
#pragma unroll
    for (int i = 0; i < 4; ++i) c[i] = acards[tid * 4 + i];
    bool mask[4]; int vals[4], suits[4]; int csize = 0; bool hasv = false;
#pragma unroll
    for (int i = 0; i < 4; ++i) {
      mask[i] = (c[i] != 0);
      if (mask[i]) { csize++; hasv = true; }
      vals[i] = mask[i] ? ((c[i] - 1) % 13 + 1) : 0;
      suits[i] = mask[i] ? ((c[i] - 1) / 13 + 1) : 0;
    }
    int fvv = mask[0] ? vals[0] : mask[1] ? vals[1] : mask[2] ? vals[2]
              : mask[3] ? vals[3] : vals[0];
    bool same = true;
#pragma unroll
    for (int i = 0; i < 4; ++i) if (mask[i] && vals[i] != fvv) same = false;
    float total = 0.f;
#pragma unroll
    for (int i = 0; i < 4; ++i) {
      if (mask[i]) {
        int v = vals[i];
        total += (v == 1) ? 1.f : (v == 11) ? 10.f : (v == 12) ? 15.f
                 : (v == 13) ? 20.f : (float)v;
      }
    }
    float uniq = 0.f;
#pragma unroll
    for (int s = 1; s <= 4; ++s) {
      bool any = false;
#pragma unroll
      for (int i = 0; i < 4; ++i) if (suits[i] == s) any = true;
      uniq += any ? 1.f : 0.f;
    }
    bool ace = false;
#pragma unroll
    for (int i = 0; i < 4; ++i) if (mask[i] && vals[i] == 1) ace = true;
    float f_same = same ? 1.f : 0.f, f_ace = ace ? 1.f : 0.f;
    float valid = (((float)csize <= 4.f) && (f_same > 0.f || f_ace > 0.f)) ? 1.f : 0.f;
    float feats[6] = {(float)csize, f_same, total, uniq, f_ace, valid};
    if (!hasv) { for (int i = 0; i < 6; ++i) feats[i] = 0.f; }
    float emb[32];
#pragma unroll
    for (int i = 0; i < 32; ++i) emb[i] = 0.f;
    float cnt = 0.f;
#pragma unroll
    for (int i = 0; i < 4; ++i) {
      float e[32];
      encode_card32(c[i], val_emb, suit_emb, type_emb, e);
      if (mask[i]) {
#pragma unroll
        for (int j = 0; j < 32; ++j) emb[j] += e[j];
        cnt += 1.f;
      }
    }
    float invc = 1.f / fmaxf(cnt, 1.f);
#pragma unroll
    for (int j = 0; j < 32; ++j)
      sW2[tid * 32 + j] = hasv ? emb[j] * invc : 0.f;      // act_emb scratch
    float t32[32];
#pragma unroll
    for (int j = 0; j < 32; ++j) {
      float acc = ce_b1[j];
#pragma unroll
      for (int k = 0; k < 6; ++k) acc += feats[k] * ce_w1[k * 32 + j];
      t32[j] = fmaxf(acc, 0.f);
    }
#pragma unroll
    for (int j = 0; j < 16; ++j) {
      float acc = ce_b2[j];
#pragma unroll
      for (int k = 0; k < 32; ++k) acc += t32[k] * ce_w2[k * 16 + j];
      sW2[960 + tid * 16 + j] = acc;                       // combo scratch
    }
    sMeta[tid] = feats[2] * 0.05f;       // strength
    sMeta[32 + tid] = hasv ? 1.f : 0.f;  // has_valid
  }
  if (tid < 32) {
    sMeta[64 + tid] = as_w3[tid];
    sMeta[96 + tid] = as_b2[tid];
  }
  __syncthreads();

  // ---------------- P1: Qa (reads sW2 scratch) + strat L1 20->64 ------------
  for (int idx = tid; idx < 1920; idx += 256) {
    int a = idx >> 6, j = idx & 63;
    float acc = as_b1[j];
#pragma unroll
    for (int k = 0; k < 32; ++k) acc += sW2[a * 32 + k] * as_w1[(128 + k) * 64 + j];
#pragma unroll
    for (int k = 0; k < 16; ++k) acc += sW2[960 + a * 16 + k] * as_w1[(160 + k) * 64 + j];
    sQa[a * QS + j] = acc;
  }
  {
    const int r = tid >> 4, j0 = (tid & 15) * 4;
    float acc[4];
#pragma unroll
    for (int j = 0; j < 4; ++j) acc[j] = se_b1[j0 + j];
    for (int k = 0; k < 20; ++k) {
      float a = sB[r * BSX + k];
#pragma unroll
      for (int j = 0; j < 4; ++j) acc[j] += a * se_w1[k * 64 + j0 + j];
    }
#pragma unroll
    for (int j = 0; j < 4; ++j) sB[r * BSX + 20 + j0 + j] = fmaxf(acc[j], 0.f);
  }
  __syncthreads();

  // ---------------- P2: strat L2 64->32 ; V = enemy@wv ; load as_w2 ---------
  {
    const int r = tid >> 4, j0 = (tid & 15) * 2;
    float acc[2] = {se_b2[j0], se_b2[j0 + 1]};
    for (int k = 0; k < 64; ++k) {
      float a = sB[r * BSX + 20 + k];
      acc[0] += a * se_w2[k * 32 + j0];
      acc[1] += a * se_w2[k * 32 + j0 + 1];
    }
    sX[r * BSX + 64 + j0] = acc[0];
    sX[r * BSX + 64 + j0 + 1] = acc[1];
    float vacc[2] = {he_bv[j0], he_bv[j0 + 1]};
    for (int k = 0; k < 32; ++k) {
      float a = sX[r * BSX + 32 + k];
      vacc[0] += a * he_wv[k * 32 + j0];
      vacc[1] += a * he_wv[k * 32 + j0 + 1];
    }
    sB[r * BSX + 100 + j0] = vacc[0];
    sB[r * BSX + 100 + j0 + 1] = vacc[1];
  }
  __syncthreads();  // Qa reads of sW2 scratch done -> safe to overwrite
  for (int idx = tid; idx < 2048; idx += 256) sW2[idx] = as_w2[idx];

  // ---------------- P3: hand_ctx = (V@wo + bo) * 8/len ----------------------
  {
    const int r = tid >> 4, j0 = (tid & 15) * 2;
    float acc[2] = {he_bo[j0], he_bo[j0 + 1]};
    for (int k = 0; k < 32; ++k) {
      float a = sB[r * BSX + 100 + k];
      acc[0] += a * he_wo[k * 32 + j0];
      acc[1] += a * he_wo[k * 32 + j0 + 1];
    }
    float scale = sLen[r];
    sX[r * BSX + j0] = scale * acc[0];
    sX[r * BSX + j0 + 1] = scale * acc[1];
  }
  __syncthreads();

  // ---------------- P4: cx L1 150->128 relu  (sX -> sB) ---------------------
  {
    const int r = tid >> 4, j0 = (tid & 15) * 8;
    float acc[8];
#pragma unroll
    for (int j = 0; j < 8; ++j) acc[j] = cx_b1[j0 + j];
    for (int k = 0; k < 150; ++k) {
      float a = sX[r * BSX + k];
      float4 w0 = *(const float4*)(cx_w1 + (size_t)k * 128 + j0);
      float4 w1 = *(const float4*)(cx_w1 + (size_t)k * 128 + j0 + 4);
      acc[0] += a * w0.x; acc[1] += a * w0.y; acc[2] += a * w0.z; acc[3] += a * w0.w;
      acc[4] += a * w1.x; acc[5] += a * w1.y; acc[6] += a * w1.z; acc[7] += a * w1.w;
    }
    __syncthreads();  // all reads of sB scratch (none here) / keep phases clean
#pragma unroll
    for (int j = 0; j < 8; ++j) sB[r * BSX + j0 + j] = fmaxf(acc[j], 0.f);
  }
  __syncthreads();

  // ---------------- P5: cx L2 128->128 relu  (sB -> sX) ---------------------
  {
    const int r = tid >> 4, j0 = (tid & 15) * 8;
    float acc[8];
#pragma unroll
    for (int j = 0; j < 8; ++j) acc[j] = cx_b2[j0 + j];
    for (int k = 0; k < 128; ++k) {
      float a = sB[r * BSX + k];
      float4 w0 = *(const float4*)(cx_w2 + (size_t)k * 128 + j0);
      float4 w1 = *(const float4*)(cx_w2 + (size_t)k * 128 + j0 + 4);
      acc[0] += a * w0.x; acc[1] += a * w0.y; acc[2] += a * w0.z; acc[3] += a * w0.w;
      acc[4] += a * w1.x; acc[5] += a * w1.y; acc[6] += a * w1.z; acc[7] += a * w1.w;
    }
    __syncthreads();  // sX cols [0:150) no longer needed after this point
#pragma unroll
    for (int j = 0; j < 8; ++j) sX[r * BSX + j0 + j] = fmaxf(acc[j], 0.f);
  }
  __syncthreads();

  // ---------------- P6: cx L3 128->128  (sX -> sB = ctx) --------------------
  {
    const int r = tid >> 4, j0 = (tid & 15) * 8;
    float acc[8];
#pragma unroll
    for (int j = 0; j < 8; ++j) acc[j] = cx_b3[j0 + j];
    for (int k = 0; k < 128; ++k) {
      float a = sX[r * BSX + k];
      float4 w0 = *(const float4*)(cx_w3 + (size_t)k * 128 + j0);
      float4 w1 = *(const float4*)(cx_w3 + (size_t)k * 128 + j0 + 4);
      acc[0] += a * w0.x; acc[1] += a * w0.y; acc[2] += a * w0.z; acc[3] += a * w0.w;
      acc[4] += a * w1.x; acc[5] += a * w1.y; acc[6] += a * w1.z; acc[7] += a * w1.w;
    }
    __syncthreads();
#pragma unroll
    for (int j = 0; j < 8; ++j) sB[r * BSX + j0 + j] = acc[j];
  }
  __syncthreads();

  // ---------------- P7: t1 = relu(ctx@atc_w1+b) ; P = ctx@as_w1[:128] -------
  {
    const int r = tid >> 4, j0 = (tid & 15) * 4;
    float accT[4], accP[4];
#pragma unroll
    for (int j = 0; j < 4; ++j) { accT[j] = atc_b1[j0 + j]; accP[j] = 0.f; }
    for (int k = 0; k < 128; ++k) {
      float a = sB[r * BSX + k];
      float4 tw = *(const float4*)(atc_w1 + (size_t)k * 64 + j0);
      float4 pw = *(const float4*)(as_w1 + (size_t)k * 64 + j0);
      accT[0] += a * tw.x; accT[1] += a * tw.y; accT[2] += a * tw.z; accT[3] += a * tw.w;
      accP[0] += a * pw.x; accP[1] += a * pw.y; accP[2] += a * pw.z; accP[3] += a * pw.w;
    }
    __syncthreads();
#pragma unroll
    for (int j = 0; j < 4; ++j) {
      sX[r * BSX + j0 + j] = fmaxf(accT[j], 0.f);   // t1 cols [0:64)
      sX[r * BSX + 64 + j0 + j] = accP[j];          // P  cols [64:128)
    }
  }
  __syncthreads();

  // ---------------- P8: type logits + softmax -------------------------------
  if (tid < MT * 4) {
    const int r = tid >> 2, j = tid & 3;
    float acc = atc_b2[j];
    for (int k = 0; k < 64; ++k) acc += sX[r * BSX + k] * atc_w2[k * 4 + j];
    sTp[r * 4 + j] = acc;
  }
  __syncthreads();
  if (tid < MT) {
    float l0 = sTp[tid * 4 + 0], l1 = sTp[tid * 4 + 1];
    float l2 = sTp[tid * 4 + 2], l3 = sTp[tid * 4 + 3];
    float m = fmaxf(fmaxf(l0, l1), fmaxf(l2, l3));
    float e0 = expf(l0 - m), e1 = expf(l1 - m), e2 = expf(l2 - m), e3 = expf(l3 - m);
    float inv = 1.f / (e0 + e1 + e2 + e3);
    sTp[tid * 4 + 0] = e0 * inv; sTp[tid * 4 + 1] = e1 * inv;
    sTp[tid * 4 + 2] = e2 * inv; sTp[tid * 4 + 3] = e3 * inv;
  }
  __syncthreads();

  // ---------------- P9: scoring (16 rows x 30 actions) ----------------------
  {
    const int r = tid >> 4, a0 = tid & 15;
    const int a1 = a0 + 16;
    const bool v1 = (a1 < 30);
    const int A1 = v1 ? a1 : 0;
    const float b3v = as_b3[0];
    const float tp0 = sTp[r * 4 + 0], tp1 = sTp[r * 4 + 1], tp3 = sTp[r * 4 + 3];
    const float* Prow = &sX[r * BSX + 64];
    const float* qa0 = &sQa[a0 * QS];
    const float* qa1 = &sQa[A1 * QS];
    float acc0[32], acc1[32];
#pragma unroll
    for (int j = 0; j < 32; ++j) { acc0[j] = 0.f; acc1[j] = 0.f; }
    for (int k = 0; k < 64; ++k) {
      float p = Prow[k];
      float s0 = fmaxf(p + qa0[k], 0.f);
      float s1 = fmaxf(p + qa1[k], 0.f);
      const float* w2r = &sW2[k * 32];
#pragma unroll
      for (int j = 0; j < 32; ++j) {
        float w = w2r[j];
        acc0[j] += s0 * w;
        acc1[j] += s1 * w;
      }
    }
    float sc0 = b3v, sc1 = b3v;
#pragma unroll
    for (int j = 0; j < 32; ++j) {
      float w3 = sMeta[64 + j], bb2 = sMeta[96 + j];
      sc0 += fmaxf(acc0[j] + bb2, 0.f) * w3;
      sc1 += fmaxf(acc1[j] + bb2, 0.f) * w3;
    }
    float st0 = sMeta[a0], hv0 = sMeta[32 + a0];
    float st1 = sMeta[A1], hv1 = sMeta[32 + A1];
    float bon0 = (hv0 > 0.5f) ? (tp0 * st0 + tp1 * (1.f - st0)) : tp3 * 2.f;
    float bon1 = (hv1 > 0.5f) ? (tp0 * st1 + tp1 * (1.f - st1)) : tp3 * 2.f;
    out[(size_t)(b0 + r) * 30 + a0] = sc0 + bon0;
    if (v1) out[(size_t)(b0 + r) * 30 + a1] = sc1 + bon1;
  }
}

// ---------------------------------------------------------------------------
extern "C" void kernel_launch(void* const* d_in, const int* in_sizes, int n_in,
                              void* d_out, int out_size, void* d_ws, size_t ws_size,
                              hipStream_t stream) {
  (void)in_sizes; (void)n_in; (void)out_size; (void)d_ws; (void)ws_size;
  const int* hand_cards = (const int*)d_in[0];
  const int* enemy_card = (const int*)d_in[1];
  const int* hand_size = (const int*)d_in[2];
  const float* game_state = (const float*)d_in[3];
  const float* discard = (const float*)d_in[4];
  const int* acards = (const int*)d_in[5];
  // d_in[6] = num_valid_actions (unused scalar)
  const float* val_emb = (const float*)d_in[7];
  const float* suit_emb = (const float*)d_in[8];
  const float* type_emb = (const float*)d_in[9];
  const float* ce_w1 = (const float*)d_in[10], * ce_b1 = (const float*)d_in[11];
  const float* ce_w2 = (const float*)d_in[12], * ce_b2 = (const float*)d_in[13];
  // d_in[14..21] = ha_* (hand self-attention) -- provably dead code, unused
  const float* he_wv = (const float*)d_in[26], * he_bv = (const float*)d_in[27];
  const float* he_wo = (const float*)d_in[28], * he_bo = (const float*)d_in[29];
  const float* se_w1 = (const float*)d_in[30], * se_b1 = (const float*)d_in[31];
  const float* se_w2 = (const float*)d_in[32], * se_b2 = (const float*)d_in[33];
  const float* atc_w1 = (const float*)d_in[34], * atc_b1 = (const float*)d_in[35];
  const float* atc_w2 = (const float*)d_in[36], * atc_b2 = (const float*)d_in[37];
  const float* as_w1 = (const float*)d_in[38], * as_b1 = (const float*)d_in[39];
  const float* as_w2 = (const float*)d_in[40], * as_b2 = (const float*)d_in[41];
  const float* as_w3 = (const float*)d_in[42], * as_b3 = (const float*)d_in[43];
  const float* cx_w1 = (const float*)d_in[44], * cx_b1 = (const float*)d_in[45];
  const float* cx_w2 = (const float*)d_in[46], * cx_b2 = (const float*)d_in[47];
  const float* cx_w3 = (const float*)d_in[48], * cx_b3 = (const float*)d_in[49];
  float* out = (float*)d_out;

  hipLaunchKernelGGL(policy_fused, dim3(16384 / MT), dim3(256), 0, stream,
                     hand_cards, enemy_card, hand_size, game_state, discard, acards,
                     val_emb, suit_emb, type_emb,
                     ce_w1, ce_b1, ce_w2, ce_b2,
                     he_wv, he_bv, he_wo, he_bo,
                     se_w1, se_b1, se_w2, se_b2,
                     atc_w1, atc_b1, atc_w2, atc_b2,
                     as_w1, as_b1, as_w2, as_b2, as_w3, as_b3,
                     cx_w1, cx_b1, cx_w2, cx_b2, cx_w3, cx_b3,
                     out);
}

// Round 3
// 298.202 us; speedup vs baseline: 1.0694x; 1.0694x over previous
//
#include <hip/hip_runtime.h>
#include <math.h>

#define MT 16        // batch rows per block -> grid 1024 (4 blocks/CU dispatchable)
#define XS 152       // sX row stride (152%32==24, odd-ish pattern; 608B row, 16B-aligned)
#define BSB 132      // sB row stride (132%32==4 -> 4 rows hit distinct banks)
#define QS 65        // sQa row stride (65%32==1 -> action rows on distinct banks)

// ---------------------------------------------------------------------------
// card encoding: ce = [val_emb[v], suit_emb[s]] + [type_emb[ct], 0...]
// ---------------------------------------------------------------------------
__device__ __forceinline__ void encode_card32(int c,
                                              const float* __restrict__ val_emb,
                                              const float* __restrict__ suit_emb,
                                              const float* __restrict__ type_emb,
                                              float* e) {
  bool inv = (c == 0) || (c == 53);
  int v = inv ? 0 : ((c - 1) % 13 + 1);
  int s = inv ? 0 : ((c - 1) / 13 + 1);
  int ct = (v == 11) ? 1 : (v == 12) ? 2 : (v == 13) ? 3 : 0;
#pragma unroll
  for (int i = 0; i < 16; ++i) e[i] = val_emb[v * 16 + i];
#pragma unroll
  for (int i = 0; i < 16; ++i) e[16 + i] = suit_emb[s * 16 + i];
#pragma unroll
  for (int i = 0; i < 8; ++i) e[i] += type_emb[ct * 8 + i];
}

#define FMA8(ACC, A, W0, W1)                                           \
  ACC[0] += (A) * (W0).x; ACC[1] += (A) * (W0).y;                      \
  ACC[2] += (A) * (W0).z; ACC[3] += (A) * (W0).w;                      \
  ACC[4] += (A) * (W1).x; ACC[5] += (A) * (W1).y;                      \
  ACC[6] += (A) * (W1).z; ACC[7] += (A) * (W1).w;

// ---------------------------------------------------------------------------
// 128-wide layer with LDS-staged weights (k-tiles of 32 rows = 16 KB).
// 256 threads: thread = (row r = tid>>4, 8 cols at j0=(tid&15)*8).
// Weight tile staged cooperatively (coalesced float4); compute reads LDS only.
// ---------------------------------------------------------------------------
template <int K, bool RELU>
__device__ __forceinline__ void layer128_lds(
    const float* __restrict__ actIn, int is, float* __restrict__ actOut, int os,
    const float* __restrict__ W, const float* __restrict__ bias,
    float* __restrict__ wbuf) {
  const int tid = threadIdx.x;
  const int r = tid >> 4, j0 = (tid & 15) * 8;
  float acc[8];
  {
    float4 b0 = *(const float4*)&bias[j0];
    float4 b1 = *(const float4*)&bias[j0 + 4];
    acc[0] = b0.x; acc[1] = b0.y; acc[2] = b0.z; acc[3] = b0.w;
    acc[4] = b1.x; acc[5] = b1.y; acc[6] = b1.z; acc[7] = b1.w;
  }
  constexpr int FT = K / 32;
  constexpr int TAIL = K - FT * 32;
  const float* aRow = actIn + r * is;
#pragma unroll 1
  for (int t = 0; t < FT; ++t) {
    const int k0 = t * 32;
    __syncthreads();  // previous wbuf contents fully consumed
#pragma unroll
    for (int p = 0; p < 4; ++p) {
      int idx = tid * 4 + p * 1024;
      *(float4*)&wbuf[idx] = *(const float4*)&W[(size_t)k0 * 128 + idx];
    }
    __syncthreads();
#pragma unroll 8
    for (int kk = 0; kk < 32; ++kk) {
      float a = aRow[k0 + kk];
      float4 w0 = *(const float4*)&wbuf[kk * 128 + j0];
      float4 w1 = *(const float4*)&wbuf[kk * 128 + j0 + 4];
      FMA8(acc, a, w0, w1);
    }
  }
  if constexpr (TAIL > 0) {
    const int k0 = FT * 32;
    __syncthreads();
    for (int idx = tid * 4; idx < TAIL * 128; idx += 1024)
      *(float4*)&wbuf[idx] = *(const float4*)&W[(size_t)k0 * 128 + idx];
    __syncthreads();
#pragma unroll
    for (int kk = 0; kk < TAIL; ++kk) {
      float a = aRow[k0 + kk];
      float4 w0 = *(const float4*)&wbuf[kk * 128 + j0];
      float4 w1 = *(const float4*)&wbuf[kk * 128 + j0 + 4];
      FMA8(acc, a, w0, w1);
    }
  }
  float4 o0, o1;
  if (RELU) {
    o0 = make_float4(fmaxf(acc[0], 0.f), fmaxf(acc[1], 0.f),
                     fmaxf(acc[2], 0.f), fmaxf(acc[3], 0.f));
    o1 = make_float4(fmaxf(acc[4], 0.f), fmaxf(acc[5], 0.f),
                     fmaxf(acc[6], 0.f), fmaxf(acc[7], 0.f));
  } else {
    o0 = make_float4(acc[0], acc[1], acc[2], acc[3]);
    o1 = make_float4(acc[4], acc[5], acc[6], acc[7]);
  }
  *(float4*)&actOut[r * os + j0] = o0;
  *(float4*)&actOut[r * os + j0 + 4] = o1;
}

// ---------------------------------------------------------------------------
// Dual 64-wide layer: t1 = relu(ctx@atc_w1 + atc_b1) into cols [0:64),
// P = ctx@as_w1[:128] into cols [64:128). Same staged-weight structure,
// atc_w1 tile in wbuf cols [0:64), as_w1 tile in cols [64:128).
// ---------------------------------------------------------------------------
__device__ __forceinline__ void layer_dual64(
    const float* __restrict__ actIn, int is, float* __restrict__ actOut, int os,
    const float* __restrict__ Wt, const float* __restrict__ bt,
    const float* __restrict__ Wp, float* __restrict__ wbuf) {
  const int tid = threadIdx.x;
  const int r = tid >> 4, j0 = (tid & 15) * 8;
  float acc[8];
  if (j0 < 64) {
    float4 b0 = *(const float4*)&bt[j0];
    float4 b1 = *(const float4*)&bt[j0 + 4];
    acc[0] = b0.x; acc[1] = b0.y; acc[2] = b0.z; acc[3] = b0.w;
    acc[4] = b1.x; acc[5] = b1.y; acc[6] = b1.z; acc[7] = b1.w;
  } else {
#pragma unroll
    for (int j = 0; j < 8; ++j) acc[j] = 0.f;
  }
  const float* aRow = actIn + r * is;
#pragma unroll 1
  for (int t = 0; t < 4; ++t) {
    const int k0 = t * 32;
    __syncthreads();
#pragma unroll
    for (int p = 0; p < 2; ++p) {
      int idx = tid * 4 + p * 1024;        // idx < 2048 = 32 rows x 64 cols
      int row = idx >> 6, c = idx & 63;
      *(float4*)&wbuf[row * 128 + c] =
          *(const float4*)&Wt[(size_t)(k0 + row) * 64 + c];
      *(float4*)&wbuf[row * 128 + 64 + c] =
          *(const float4*)&Wp[(size_t)(k0 + row) * 64 + c];
    }
    __syncthreads();
#pragma unroll 8
    for (int kk = 0; kk < 32; ++kk) {
      float a = aRow[k0 + kk];
      float4 w0 = *(const float4*)&wbuf[kk * 128 + j0];
      float4 w1 = *(const float4*)&wbuf[kk * 128 + j0 + 4];
      FMA8(acc, a, w0, w1);
    }
  }
  float4 o0, o1;
  if (j0 < 64) {  // t1 half: relu
    o0 = make_float4(fmaxf(acc[0], 0.f), fmaxf(acc[1], 0.f),
                     fmaxf(acc[2], 0.f), fmaxf(acc[3], 0.f));
    o1 = make_float4(fmaxf(acc[4], 0.f), fmaxf(acc[5], 0.f),
                     fmaxf(acc[6], 0.f), fmaxf(acc[7], 0.f));
  } else {        // P half: linear
    o0 = make_float4(acc[0], acc[1], acc[2], acc[3]);
    o1 = make_float4(acc[4], acc[5], acc[6], acc[7]);
  }
  *(float4*)&actOut[r * os + j0] = o0;
  *(float4*)&actOut[r * os + j0 + 4] = o1;
}

// ---------------------------------------------------------------------------
// Fused kernel. 16 rows/block, 256 threads, grid 1024. LDS ~51.4 KB -> 3 blk/CU.
//   sX[r]: [0:32) hand_ctx | [32:64) enemy | [64:96) strat_ctx | [96:150) discard
//          later: h1-chain buffer; finally [0:64) t1, [64:128) P
//   sB[r]: [0:20) strat_in | [20:84) t64 | [84:116) V ; later ping-pong buffer
//   wbuf : action scratch (act_emb [0:960), combo [960:1440)), then weight tiles
//   sQa[30][65], sW2 = as_w2, sMeta: strength/hasv/w3/b2
// ---------------------------------------------------------------------------
__global__ __launch_bounds__(256) void policy_fused(
    const int* __restrict__ hand_cards, const int* __restrict__ enemy_card,
    const int* __restrict__ hand_size, const float* __restrict__ game_state,
    const float* __restrict__ discard, const int* __restrict__ acards,
    const float* __restrict__ val_emb, const float* __restrict__ suit_emb,
    const float* __restrict__ type_emb,
    const float* __restrict__ ce_w1, const float* __restrict__ ce_b1,
    const float* __restrict__ ce_w2, const float* __restrict__ ce_b2,
    const float* __restrict__ he_wv, const float* __restrict__ he_bv,
    const float* __restrict__ he_wo, const float* __restrict__ he_bo,
    const float* __restrict__ se_w1, const float* __restrict__ se_b1,
    const float* __restrict__ se_w2, const float* __restrict__ se_b2,
    const float* __restrict__ atc_w1, const float* __restrict__ atc_b1,
    const float* __restrict__ atc_w2, const float* __restrict__ atc_b2,
    const float* __restrict__ as_w1, const float* __restrict__ as_b1,
    const float* __restrict__ as_w2, const float* __restrict__ as_b2,
    const float* __restrict__ as_w3, const float* __restrict__ as_b3,
    const float* __restrict__ cx_w1, const float* __restrict__ cx_b1,
    const float* __restrict__ cx_w2, const float* __restrict__ cx_b2,
    const float* __restrict__ cx_w3, const float* __restrict__ cx_b3,
    float* __restrict__ out) {
  __shared__ float sX[MT * XS];      // 9728 B
  __shared__ float sB[MT * BSB];     // 8448 B
  __shared__ float wbuf[4096];       // 16384 B
  __shared__ float sQa[30 * QS];     // 7800 B
  __shared__ float sW2[2048];        // 8192 B
  __shared__ float sMeta[128];       // strength[0:32) hasv[32:64) w3[64:96) b2[96:128)
  __shared__ float sTp[MT * 4];
  __shared__ float sLen[MT];

  const int tid = threadIdx.x;
  const int b0 = blockIdx.x * MT;

  // ---------------- P0: global gathers + per-row features + action features --
  for (int idx = tid; idx < MT * 54; idx += 256) {
    int r = idx / 54, k = idx - r * 54;
    sX[r * XS + 96 + k] = discard[(size_t)b0 * 54 + idx];
  }
  for (int idx = tid; idx < MT * 10; idx += 256) {
    int r = idx / 10, k = idx - r * 10;
    sB[r * BSB + k] = game_state[(size_t)b0 * 10 + idx];
  }
  if (tid < MT) {
    const int b = b0 + tid;
    const float hsz = (float)hand_size[b];
    sLen[tid] = 8.0f / fmaxf(hsz, 1.0f);
    int aces = 0, faces = 0, low = 0, c1 = 0, c2 = 0, c3 = 0, c4 = 0;
#pragma unroll
    for (int i = 0; i < 8; ++i) {
      int c = hand_cards[b * 8 + i];
      int v = (c == 0) ? 0 : ((c - 1) % 13 + 1);
      int s = (c == 0) ? 0 : ((c - 1) / 13 + 1);
      aces += (v == 1);
      faces += (v >= 11 && v <= 13);
      low += (v >= 2 && v <= 6);
      c1 += (s == 1); c2 += (s == 2); c3 += (s == 3); c4 += (s == 4);
    }
    float sdiv = (float)((c1 > 0) + (c2 > 0) + (c3 > 0) + (c4 > 0)) * 0.25f;
    float hvr = (float)faces / (hsz + 1e-8f);
    float* si = &sB[tid * BSB];
    si[10] = hsz; si[11] = (float)aces; si[12] = (float)faces;
    si[13] = (float)low; si[14] = (float)c1; si[15] = (float)c2;
    si[16] = (float)c3; si[17] = (float)c4; si[18] = hvr; si[19] = sdiv;
    float e[32];
    encode_card32(enemy_card[b], val_emb, suit_emb, type_emb, e);
#pragma unroll
    for (int i = 0; i < 32; ++i) sX[tid * XS + 32 + i] = e[i];
  }
  if (tid < 30) {  // action features -> wbuf scratch + sMeta
    int c[4];
#pragma unroll
    for (int i = 0; i < 4; ++i) c[i] = acards[tid * 4 + i];
    bool mask[4]; int vals[4], suits[4]; int csize = 0; bool hasv = false;
#pragma unroll
    for (int i = 0; i < 4; ++i) {
      mask[i] = (c[i] != 0);
      if (mask[i]) { csize++; hasv = true; }
      vals[i] = mask[i] ? ((c[i] - 1) % 13 + 1) : 0;
      suits[i] = mask[i] ? ((c[i] - 1) / 13 + 1) : 0;
    }
    int fvv = mask[0] ? vals[0] : mask[1] ? vals[1] : mask[2] ? vals[2]
              : mask[3] ? vals[3] : vals[0];
    bool same = true;
#pragma unroll
    for (int i = 0; i < 4; ++i) if (mask[i] && vals[i] != fvv) same = false;
    float total = 0.f;
#pragma unroll
    for (int i = 0; i < 4; ++i) {
      if (mask[i]) {
        int v = vals[i];
        total += (v == 1) ? 1.f : (v == 11) ? 10.f : (v == 12) ? 15.f
                 : (v == 13) ? 20.f : (float)v;
      }
    }
    float uniq = 0.f;
#pragma unroll
    for (int s = 1; s <= 4; ++s) {
      bool any = false;
#pragma unroll
      for (int i = 0; i < 4; ++i) if (suits[i] == s) any = true;
      uniq += any ? 1.f : 0.f;
    }
    bool ace = false;
#pragma unroll
    for (int i = 0; i < 4; ++i) if (mask[i] && vals[i] == 1) ace = true;
    float f_same = same ? 1.f : 0.f, f_ace = ace ? 1.f : 0.f;
    float valid = (((float)csize <= 4.f) && (f_same > 0.f || f_ace > 0.f)) ? 1.f : 0.f;
    float feats[6] = {(float)csize, f_same, total, uniq, f_ace, valid};
    if (!hasv) { for (int i = 0; i < 6; ++i) feats[i] = 0.f; }
    float emb[32];
#pragma unroll
    for (int i = 0; i < 32; ++i) emb[i] = 0.f;
    float cnt = 0.f;
#pragma unroll
    for (int i = 0; i < 4; ++i) {
      float e[32];
      encode_card32(c[i], val_emb, suit_emb, type_emb, e);
      if (mask[i]) {
#pragma unroll
        for (int j = 0; j < 32; ++j) emb[j] += e[j];
        cnt += 1.f;
      }
    }
    float invc = 1.f / fmaxf(cnt, 1.f);
#pragma unroll
    for (int j = 0; j < 32; ++j)
      wbuf[tid * 32 + j] = hasv ? emb[j] * invc : 0.f;     // act_emb scratch
    float t32[32];
#pragma unroll
    for (int j = 0; j < 32; ++j) {
      float acc = ce_b1[j];
#pragma unroll
      for (int k = 0; k < 6; ++k) acc += feats[k] * ce_w1[k * 32 + j];
      t32[j] = fmaxf(acc, 0.f);
    }
#pragma unroll
    for (int j = 0; j < 16; ++j) {
      float acc = ce_b2[j];
#pragma unroll
      for (int k = 0; k < 32; ++k) acc += t32[k] * ce_w2[k * 16 + j];
      wbuf[960 + tid * 16 + j] = acc;                      // combo scratch
    }
    sMeta[tid] = feats[2] * 0.05f;       // strength
    sMeta[32 + tid] = hasv ? 1.f : 0.f;  // has_valid
  }
  if (tid < 32) {
    sMeta[64 + tid] = as_w3[tid];
    sMeta[96 + tid] = as_b2[tid];
  }
  __syncthreads();

  // ---------------- P1: Qa (wbuf scratch -> sQa); se L1; load as_w2 ---------
  for (int idx = tid; idx < 1920; idx += 256) {
    int a = idx >> 6, j = idx & 63;
    float acc = as_b1[j];
#pragma unroll
    for (int k = 0; k < 32; ++k) acc += wbuf[a * 32 + k] * as_w1[(128 + k) * 64 + j];
#pragma unroll
    for (int k = 0; k < 16; ++k) acc += wbuf[960 + a * 16 + k] * as_w1[(160 + k) * 64 + j];
    sQa[a * QS + j] = acc;
  }
  {
    const int r = tid >> 4, j0 = (tid & 15) * 4;
    float acc[4];
#pragma unroll
    for (int j = 0; j < 4; ++j) acc[j] = se_b1[j0 + j];
    for (int k = 0; k < 20; ++k) {
      float a = sB[r * BSB + k];
#pragma unroll
      for (int j = 0; j < 4; ++j) acc[j] += a * se_w1[k * 64 + j0 + j];
    }
#pragma unroll
    for (int j = 0; j < 4; ++j) sB[r * BSB + 20 + j0 + j] = fmaxf(acc[j], 0.f);
  }
  for (int idx = tid; idx < 2048; idx += 256) sW2[idx] = as_w2[idx];
  __syncthreads();

  // ---------------- P2: se L2 64->32 -> sX[64:96) ; V = enemy@wv -> sB[84:116)
  {
    const int r = tid >> 4, j0 = (tid & 15) * 2;
    float acc[2] = {se_b2[j0], se_b2[j0 + 1]};
    for (int k = 0; k < 64; ++k) {
      float a = sB[r * BSB + 20 + k];
      acc[0] += a * se_w2[k * 32 + j0];
      acc[1] += a * se_w2[k * 32 + j0 + 1];
    }
    sX[r * XS + 64 + j0] = acc[0];
    sX[r * XS + 64 + j0 + 1] = acc[1];
    float vacc[2] = {he_bv[j0], he_bv[j0 + 1]};
    for (int k = 0; k < 32; ++k) {
      float a = sX[r * XS + 32 + k];
      vacc[0] += a * he_wv[k * 32 + j0];
      vacc[1] += a * he_wv[k * 32 + j0 + 1];
    }
    sB[r * BSB + 84 + j0] = vacc[0];
    sB[r * BSB + 84 + j0 + 1] = vacc[1];
  }
  __syncthreads();

  // ---------------- P3: hand_ctx = (V@wo + bo) * 8/len -> sX[0:32) ----------
  {
    const int r = tid >> 4, j0 = (tid & 15) * 2;
    float acc[2] = {he_bo[j0], he_bo[j0 + 1]};
    for (int k = 0; k < 32; ++k) {
      float a = sB[r * BSB + 84 + k];
      acc[0] += a * he_wo[k * 32 + j0];
      acc[1] += a * he_wo[k * 32 + j0 + 1];
    }
    float scale = sLen[r];
    sX[r * XS + j0] = scale * acc[0];
    sX[r * XS + j0 + 1] = scale * acc[1];
  }
  // no barrier: layer's internal stage-barrier orders everything

  // ---------------- P4..P6: context MLP chain (LDS-staged weights) ----------
  layer128_lds<150, true>(sX, XS, sB, BSB, cx_w1, cx_b1, wbuf);
  layer128_lds<128, true>(sB, BSB, sX, XS, cx_w2, cx_b2, wbuf);
  layer128_lds<128, false>(sX, XS, sB, BSB, cx_w3, cx_b3, wbuf);

  // ---------------- P7: t1 | P from ctx (dual staged layer) -----------------
  layer_dual64(sB, BSB, sX, XS, atc_w1, atc_b1, as_w1, wbuf);
  __syncthreads();

  // ---------------- P8: type logits + softmax -------------------------------
  if (tid < MT * 4) {
    const int r = tid >> 2, j = tid & 3;
    float acc = atc_b2[j];
    for (int k = 0; k < 64; ++k) acc += sX[r * XS + k] * atc_w2[k * 4 + j];
    sTp[r * 4 + j] = acc;
  }
  __syncthreads();
  if (tid < MT) {
    float l0 = sTp[tid * 4 + 0], l1 = sTp[tid * 4 + 1];
    float l2 = sTp[tid * 4 + 2], l3 = sTp[tid * 4 + 3];
    float m = fmaxf(fmaxf(l0, l1), fmaxf(l2, l3));
    float e0 = expf(l0 - m), e1 = expf(l1 - m), e2 = expf(l2 - m), e3 = expf(l3 - m);
    float inv = 1.f / (e0 + e1 + e2 + e3);
    sTp[tid * 4 + 0] = e0 * inv; sTp[tid * 4 + 1] = e1 * inv;
    sTp[tid * 4 + 2] = e2 * inv; sTp[tid * 4 + 3] = e3 * inv;
  }
  __syncthreads();

  // ---------------- P9: scoring (16 rows x 30 actions) ----------------------
  {
    const int r = tid >> 4, a0 = tid & 15;
    const int a1 = a0 + 16;
    const bool v1 = (a1 < 30);
    const int A1 = v1 ? a1 : 0;
    const float b3v = as_b3[0];
    const float tp0 = sTp[r * 4 + 0], tp1 = sTp[r * 4 + 1], tp3 = sTp[r * 4 + 3];
    const float* Prow = &sX[r * XS + 64];
    const float* qa0 = &sQa[a0 * QS];
    const float* qa1 = &sQa[A1 * QS];
    float acc0[32], acc1[32];
#pragma unroll
    for (int j = 0; j < 32; ++j) { acc0[j] = 0.f; acc1[j] = 0.f; }
#pragma unroll 4
    for (int k = 0; k < 64; ++k) {
      float p = Prow[k];
      float s0 = fmaxf(p + qa0[k], 0.f);
      float s1 = fmaxf(p + qa1[k], 0.f);
      const float* w2r = &sW2[k * 32];
#pragma unroll
      for (int j = 0; j < 32; ++j) {
        float w = w2r[j];
        acc0[j] += s0 * w;
        acc1[j] += s1 * w;
      }
    }
    float sc0 = b3v, sc1 = b3v;
#pragma unroll
    for (int j = 0; j < 32; ++j) {
      float w3 = sMeta[64 + j], bb2 = sMeta[96 + j];
      sc0 += fmaxf(acc0[j] + bb2, 0.f) * w3;
      sc1 += fmaxf(acc1[j] + bb2, 0.f) * w3;
    }
    float st0 = sMeta[a0], hv0 = sMeta[32 + a0];
    float st1 = sMeta[A1], hv1 = sMeta[32 + A1];
    float bon0 = (hv0 > 0.5f) ? (tp0 * st0 + tp1 * (1.f - st0)) : tp3 * 2.f;
    float bon1 = (hv1 > 0.5f) ? (tp0 * st1 + tp1 * (1.f - st1)) : tp3 * 2.f;
    out[(size_t)(b0 + r) * 30 + a0] = sc0 + bon0;
    if (v1) out[(size_t)(b0 + r) * 30 + a1] = sc1 + bon1;
  }
}

// ---------------------------------------------------------------------------
extern "C" void kernel_launch(void* const* d_in, const int* in_sizes, int n_in,
                              void* d_out, int out_size, void* d_ws, size_t ws_size,
                              hipStream_t stream) {
  (void)in_sizes; (void)n_in; (void)out_size; (void)d_ws; (void)ws_size;
  const int* hand_cards = (const int*)d_in[0];
  const int* enemy_card = (const int*)d_in[1];
  const int* hand_size = (const int*)d_in[2];
  const float* game_state = (const float*)d_in[3];
  const float* discard = (const float*)d_in[4];
  const int* acards = (const int*)d_in[5];
  // d_in[6] = num_valid_actions (unused scalar)
  const float* val_emb = (const float*)d_in[7];
  const float* suit_emb = (const float*)d_in[8];
  const float* type_emb = (const float*)d_in[9];
  const float* ce_w1 = (const float*)d_in[10], * ce_b1 = (const float*)d_in[11];
  const float* ce_w2 = (const float*)d_in[12], * ce_b2 = (const float*)d_in[13];
  // d_in[14..21] = ha_* (hand self-attention) -- provably dead code, unused
  const float* he_wv = (const float*)d_in[26], * he_bv = (const float*)d_in[27];
  const float* he_wo = (const float*)d_in[28], * he_bo = (const float*)d_in[29];
  const float* se_w1 = (const float*)d_in[30], * se_b1 = (const float*)d_in[31];
  const float* se_w2 = (const float*)d_in[32], * se_b2 = (const float*)d_in[33];
  const float* atc_w1 = (const float*)d_in[34], * atc_b1 = (const float*)d_in[35];
  const float* atc_w2 = (const float*)d_in[36], * atc_b2 = (const float*)d_in[37];
  const float* as_w1 = (const float*)d_in[38], * as_b1 = (const float*)d_in[39];
  const float* as_w2 = (const float*)d_in[40], * as_b2 = (const float*)d_in[41];
  const float* as_w3 = (const float*)d_in[42], * as_b3 = (const float*)d_in[43];
  const float* cx_w1 = (const float*)d_in[44], * cx_b1 = (const float*)d_in[45];
  const float* cx_w2 = (const float*)d_in[46], * cx_b2 = (const float*)d_in[47];
  const float* cx_w3 = (const float*)d_in[48], * cx_b3 = (const float*)d_in[49];
  float* out = (float*)d_out;

  hipLaunchKernelGGL(policy_fused, dim3(16384 / MT), dim3(256), 0, stream,
                     hand_cards, enemy_card, hand_size, game_state, discard, acards,
                     val_emb, suit_emb, type_emb,
                     ce_w1, ce_b1, ce_w2, ce_b2,
                     he_wv, he_bv, he_wo, he_bo,
                     se_w1, se_b1, se_w2, se_b2,
                     atc_w1, atc_b1, atc_w2, atc_b2,
                     as_w1, as_b1, as_w2, as_b2, as_w3, as_b3,
                     cx_w1, cx_b1, cx_w2, cx_b2, cx_w3, cx_b3,
                     out);
}